// Round 1
// baseline (1281.539 us; speedup 1.0000x reference)
//
#include <hip/hip_runtime.h>

#define T_STEPS 512
#define NB 4          // batches per block
#define LPB 16        // lanes per batch
#define GPL 5         // gate rows per lane (16*5 = 80)
#define HS 20         // hidden size
#define G4 80         // 4*HS gates
#define F0 10         // input features (layer 0)

__device__ __forceinline__ float sigmoid_fast(float v) {
    return __fdividef(1.f, 1.f + __expf(-v));
}
__device__ __forceinline__ float tanh_fast(float v) {
    // 1 - 2/(e^{2v}+1); saturates correctly at +-1 for large |v|
    return 1.f - __fdividef(2.f, __expf(2.f * v) + 1.f);
}

__global__ __launch_bounds__(64, 1)
void lstm2_fc_kernel(const float* __restrict__ x,
                     const float* __restrict__ wih0, const float* __restrict__ whh0,
                     const float* __restrict__ bih0, const float* __restrict__ bhh0,
                     const float* __restrict__ wih1, const float* __restrict__ whh1,
                     const float* __restrict__ bih1, const float* __restrict__ bhh1,
                     const float* __restrict__ wfc,  const float* __restrict__ bfc,
                     float* __restrict__ out)
{
    const int tid = threadIdx.x;
    const int b   = tid >> 4;      // 0..3   batch within block
    const int l   = tid & 15;      // 0..15  lane within batch
    const int g0  = l * GPL;       // first of 5 gate rows
    const int bg  = blockIdx.x * NB + b;   // global batch index

    __shared__ float s_wih1[G4 * HS];   // layer1 input weights (LDS broadcast)
    __shared__ float s_h0[NB][HS];
    __shared__ float s_h1[NB][HS];
    __shared__ float s_gates[NB][G4];

    for (int i = tid; i < G4 * HS; i += 64) s_wih1[i] = wih1[i];
    for (int i = tid; i < NB * HS; i += 64) {
        (&s_h0[0][0])[i] = 0.f;
        (&s_h1[0][0])[i] = 0.f;
    }

    // ---- per-lane register weight cache (loop-invariant) ----
    float rwih0[GPL][F0], rwhh0[GPL][HS], rwhh1[GPL][HS], rb0[GPL], rb1[GPL];
    #pragma unroll
    for (int k = 0; k < GPL; ++k) {
        const int g = g0 + k;
        #pragma unroll
        for (int f = 0; f < F0; ++f) rwih0[k][f] = wih0[g * F0 + f];
        #pragma unroll
        for (int j = 0; j < HS; ++j) rwhh0[k][j] = whh0[g * HS + j];
        #pragma unroll
        for (int j = 0; j < HS; ++j) rwhh1[k][j] = whh1[g * HS + j];
        rb0[k] = bih0[g] + bhh0[g];
        rb1[k] = bih1[g] + bhh1[g];
    }

    // ---- cell-state update items: item A = tid (all lanes), item B = 64+tid (tid<16) ----
    const int bA = tid / 20, uA = tid % 20;
    const int bB = (64 + tid) / 20, uB = (64 + tid) % 20;   // valid only for tid<16
    float cA0 = 0.f, cA1 = 0.f, cB0 = 0.f, cB1 = 0.f;

    const float* xb = x + (size_t)bg * T_STEPS * F0;
    float xc[F0], xn[F0];
    #pragma unroll
    for (int f = 0; f < F0; ++f) xc[f] = xb[f];

    __syncthreads();

    for (int t = 0; t < T_STEPS; ++t) {
        // prefetch next timestep's input (uniform across the 16 lanes of a batch)
        if (t + 1 < T_STEPS) {
            #pragma unroll
            for (int f = 0; f < F0; ++f) xn[f] = xb[(t + 1) * F0 + f];
        }

        // ================= layer 0 : gates =================
        float acc[GPL];
        #pragma unroll
        for (int k = 0; k < GPL; ++k) acc[k] = rb0[k];
        #pragma unroll
        for (int f = 0; f < F0; ++f) {
            const float xf = xc[f];
            #pragma unroll
            for (int k = 0; k < GPL; ++k) acc[k] = fmaf(xf, rwih0[k][f], acc[k]);
        }
        #pragma unroll
        for (int j = 0; j < HS; ++j) {
            const float hj = s_h0[b][j];
            #pragma unroll
            for (int k = 0; k < GPL; ++k) acc[k] = fmaf(hj, rwhh0[k][j], acc[k]);
        }
        #pragma unroll
        for (int k = 0; k < GPL; ++k) s_gates[b][g0 + k] = acc[k];
        __syncthreads();

        // ================= layer 0 : cell update =================
        {
            const float gi = s_gates[bA][uA];
            const float gf = s_gates[bA][20 + uA];
            const float gg = s_gates[bA][40 + uA];
            const float go = s_gates[bA][60 + uA];
            const float ii = sigmoid_fast(gi), ff = sigmoid_fast(gf);
            const float gz = tanh_fast(gg),    oo = sigmoid_fast(go);
            cA0 = ff * cA0 + ii * gz;
            s_h0[bA][uA] = oo * tanh_fast(cA0);
        }
        if (tid < 16) {
            const float gi = s_gates[bB][uB];
            const float gf = s_gates[bB][20 + uB];
            const float gg = s_gates[bB][40 + uB];
            const float go = s_gates[bB][60 + uB];
            const float ii = sigmoid_fast(gi), ff = sigmoid_fast(gf);
            const float gz = tanh_fast(gg),    oo = sigmoid_fast(go);
            cB0 = ff * cB0 + ii * gz;
            s_h0[bB][uB] = oo * tanh_fast(cB0);
        }
        __syncthreads();

        // ================= layer 1 : gates =================
        #pragma unroll
        for (int k = 0; k < GPL; ++k) acc[k] = rb1[k];
        #pragma unroll
        for (int j = 0; j < HS; ++j) {
            const float hj = s_h0[b][j];     // layer1 input = layer0 output (this t)
            #pragma unroll
            for (int k = 0; k < GPL; ++k)
                acc[k] = fmaf(hj, s_wih1[(g0 + k) * HS + j], acc[k]);
        }
        #pragma unroll
        for (int j = 0; j < HS; ++j) {
            const float hj = s_h1[b][j];
            #pragma unroll
            for (int k = 0; k < GPL; ++k) acc[k] = fmaf(hj, rwhh1[k][j], acc[k]);
        }
        #pragma unroll
        for (int k = 0; k < GPL; ++k) s_gates[b][g0 + k] = acc[k];
        __syncthreads();

        // ================= layer 1 : cell update =================
        {
            const float gi = s_gates[bA][uA];
            const float gf = s_gates[bA][20 + uA];
            const float gg = s_gates[bA][40 + uA];
            const float go = s_gates[bA][60 + uA];
            const float ii = sigmoid_fast(gi), ff = sigmoid_fast(gf);
            const float gz = tanh_fast(gg),    oo = sigmoid_fast(go);
            cA1 = ff * cA1 + ii * gz;
            s_h1[bA][uA] = oo * tanh_fast(cA1);
        }
        if (tid < 16) {
            const float gi = s_gates[bB][uB];
            const float gf = s_gates[bB][20 + uB];
            const float gg = s_gates[bB][40 + uB];
            const float go = s_gates[bB][60 + uB];
            const float ii = sigmoid_fast(gi), ff = sigmoid_fast(gf);
            const float gz = tanh_fast(gg),    oo = sigmoid_fast(go);
            cB1 = ff * cB1 + ii * gz;
            s_h1[bB][uB] = oo * tanh_fast(cB1);
        }
        __syncthreads();

        #pragma unroll
        for (int f = 0; f < F0; ++f) xc[f] = xn[f];
    }

    // ================= final FC: out[bg] = h1[b] . wfc + bfc =================
    if (l == 0) {
        float o = bfc[0];
        #pragma unroll
        for (int u = 0; u < HS; ++u) o = fmaf(s_h1[b][u], wfc[u], o);
        out[bg] = o;
    }
}

extern "C" void kernel_launch(void* const* d_in, const int* in_sizes, int n_in,
                              void* d_out, int out_size, void* d_ws, size_t ws_size,
                              hipStream_t stream) {
    const float* x    = (const float*)d_in[0];
    const float* wih0 = (const float*)d_in[1];
    const float* whh0 = (const float*)d_in[2];
    const float* bih0 = (const float*)d_in[3];
    const float* bhh0 = (const float*)d_in[4];
    const float* wih1 = (const float*)d_in[5];
    const float* whh1 = (const float*)d_in[6];
    const float* bih1 = (const float*)d_in[7];
    const float* bhh1 = (const float*)d_in[8];
    const float* wfc  = (const float*)d_in[9];
    const float* bfc  = (const float*)d_in[10];
    float* out = (float*)d_out;

    dim3 grid(4096 / NB), block(64);
    hipLaunchKernelGGL(lstm2_fc_kernel, grid, block, 0, stream,
                       x, wih0, whh0, bih0, bhh0,
                       wih1, whh1, bih1, bhh1, wfc, bfc, out);
}